// Round 1
// 312.890 us; speedup vs baseline: 1.0692x; 1.0692x over previous
//
#include <hip/hip_runtime.h>
#include <hip/hip_bf16.h>

// GraphSage: 3x SAGEConv(mean) + linear head.
// r18: aggregate gather de-serialized + CSR build fused.
//   - CSR rows PADDED to multiple of 8 with sentinel src=NN (row NN of h_hi is
//     zeroed once): the gather loop is always full-width (16-deep main + at most
//     one 8-step), no 4-deep/1-deep latency-exposed tails. Pad loads all hit one
//     L1-resident 256B zero row -> no extra HBM traffic; true deg still divides.
//   - uint2 gathers: lane=(edge parity, col quad), 8B/lane, one wave-load covers
//     TWO edges (half the load instrs + addr math of r17's u32 scheme); halves
//     combined with one shfl_xor(32) per accumulator at the end.
//   - perm segments 16B-aligned (pad-8 + PCAP mult of 8) -> 16 srcs loaded as
//     two uniform uint4 loads (scalarizable) instead of 16 broadcast ushorts.
//   - CSR build: hist/colscan/total/addbase/scatter (5 kernels, 3 edge passes)
//     fused into ONE kernel using fixed bucket regions b*BCAP + per-block LDS
//     hist + one global atomicAdd range reservation per (block,bucket).
//     BCAP=6144 vs mean 4096 (sd~64, fixed-seed input) -> 32 sigma. Padded perm
//     bucket mean ~4992 (sd~74) vs PCAP=6144 -> 15 sigma.
// Structure: SEPARATE aggregate and GEMM (r12 fusion starved the gather).
// XCD affinity NOT controllable from HIP (r14/r15) — do not retry.
// GEMM: weight-stationary MFMA, 2 ct/wave, 256 thr, GRID-STRIDE loop, all 16
//   A dwordx4 loads prefetched per tile. Grid-stride loop is load-bearing:
//   keeps 128-VGPR B set live (r6/r11: removing it demotes B -> 65-75us).
// Head fused into layer-2 GEMM. packed[] aliases sbuf-hi (disjoint lifetime).

constexpr int NN = 50000;
constexpr int NE = 800000;
constexpr int NTILE = NN / 16;          // 3125 exact
constexpr int EPB = 4096;
constexpr int NBLK = (NE + EPB - 1) / EPB;   // 196
constexpr int NBUCK = 196;                   // ceil(NN/256)
constexpr int BCAP = 6144;   // packed bucket capacity (edges); mean 4096
constexpr int PCAP = 6144;   // padded perm bucket capacity; mean ~4992, mult of 8

using bf16x8 = __attribute__((ext_vector_type(8))) short;
using f32x4  = __attribute__((ext_vector_type(4))) float;

__device__ __forceinline__ unsigned short bf16_rne(float f) {
    unsigned u = __float_as_uint(f);
    unsigned r = (u + 0x7FFFu + ((u >> 16) & 1u)) >> 16;
    return (unsigned short)r;
}
__device__ __forceinline__ float bf16_f(unsigned short h) {
    return __uint_as_float(((unsigned)h) << 16);
}
__device__ __forceinline__ unsigned pack_split(float v) {
    unsigned short hi = bf16_rne(v);
    float r = v - bf16_f(hi);
    unsigned short lo = bf16_rne(r);
    return (((unsigned)hi) << 16) | (unsigned)lo;
}

// ---------------- init (out bias, bucket counters, zero sentinel row) -------

__global__ __launch_bounds__(256) void k_init(float* __restrict__ out,
        const float* __restrict__ bf, int* __restrict__ bcnt,
        unsigned short* __restrict__ hhi) {
    int i = blockIdx.x * blockDim.x + threadIdx.x;
    if (i < NN) out[i] = bf[0];
    if (i < 256) bcnt[i] = 0;
    if (i < 128) hhi[(size_t)NN * 128 + i] = 0;   // sentinel row for pad edges
}

// ---------------- CSR build: one-pass bucket scatter ----------------
// Fixed bucket regions (b*BCAP). Per block: LDS hist of its 4096 edges, ONE
// global atomicAdd per touched bucket to reserve a range, scatter from LDS.

__global__ __launch_bounds__(256) void k_build_buckets(const int* __restrict__ ei,
        int* __restrict__ bcnt, unsigned* __restrict__ packed) {
    __shared__ unsigned stage[EPB];   // 16KB
    __shared__ int h[256];
    __shared__ int cur[256];
    int t = threadIdx.x;
    h[t] = 0;
    __syncthreads();
    int e0 = blockIdx.x * EPB;
    int e1 = e0 + EPB; if (e1 > NE) e1 = NE;
    for (int e = e0 + t; e < e1; e += 256) {
        int s = ei[e];
        int d = ei[NE + e];
        stage[e - e0] = ((unsigned)d << 16) | (unsigned)s;
        atomicAdd(&h[d >> 8], 1);
    }
    __syncthreads();
    if (t < NBUCK) cur[t] = t * BCAP + atomicAdd(&bcnt[t], h[t]);
    __syncthreads();
    for (int e = e0 + t; e < e1; e += 256) {
        unsigned r = stage[e - e0];
        int pos = atomicAdd(&cur[r >> 24], 1);   // bucket = d>>8 = r>>24
        packed[pos] = r;
    }
}

// Per bucket: LDS counting sort by (d&255) with PER-NODE PADDING to mult of 8;
// pad slots filled with sentinel NN. row_start points into b*PCAP region.
__global__ __launch_bounds__(256) void k_bucket_csr(const unsigned* __restrict__ packed,
        const int* __restrict__ bcnt, unsigned short* __restrict__ perm,
        int* __restrict__ cnt, int* __restrict__ row_start) {
    __shared__ unsigned recs[BCAP];       // 24KB
    __shared__ unsigned short outs[PCAP]; // 12KB
    __shared__ int cntL[256];
    __shared__ int ws[4];
    __shared__ int totS;
    int b = blockIdx.x;
    int m = bcnt[b];
    if (m > BCAP) m = BCAP;
    int t = threadIdx.x;
    cntL[t] = 0;
    __syncthreads();
    int lo = b * BCAP;
    for (int i = t; i < m; i += 256) {
        unsigned r = packed[lo + i];
        recs[i] = r;
        atomicAdd(&cntL[(r >> 16) & 255], 1);
    }
    __syncthreads();
    int lane = t & 63, wave = t >> 6;
    int orig = cntL[t];
    int pc = (orig + 7) & ~7;            // padded per-node degree
    int v = pc;
    for (int o = 1; o < 64; o <<= 1) { int u = __shfl_up(v, o); if (lane >= o) v += u; }
    if (lane == 63) ws[wave] = v;
    __syncthreads();
    int off = 0;
    for (int w = 0; w < wave; ++w) off += ws[w];
    int st = v + off - pc;               // exclusive scan of padded degrees
    int node = b * 256 + t;
    if (node < NN) { cnt[node] = orig; row_start[node] = b * PCAP + st; }
    if (t == 255) totS = st + pc;
    __syncthreads();
    cntL[t] = st;
    __syncthreads();
    for (int i = t; i < m; i += 256) {
        unsigned r = recs[i];
        int pos = atomicAdd(&cntL[(r >> 16) & 255], 1);
        outs[pos] = (unsigned short)(r & 0xFFFFu);
    }
    // pad fill: disjoint from scatter's regions, no barrier needed in between
    for (int i = st + orig; i < st + pc; ++i) outs[i] = (unsigned short)NN;
    __syncthreads();
    int totp = totS;
    for (int i = t; i < totp; i += 256)
        perm[b * PCAP + i] = outs[i];
}

// ---------------- packing ----------------

__global__ void k_pack_x(const float* __restrict__ x,
                         unsigned short* __restrict__ hhi,
                         unsigned short* __restrict__ hlo) {
    int i = blockIdx.x * blockDim.x + threadIdx.x;
    constexpr int TOT = NN * 128 / 4;
    if (i < TOT) {
        float4 v = ((const float4*)x)[i];
        unsigned p0 = pack_split(v.x), p1 = pack_split(v.y);
        unsigned p2 = pack_split(v.z), p3 = pack_split(v.w);
        uint2 hi, lo;
        hi.x = (p0 >> 16) | (p1 & 0xFFFF0000u);
        hi.y = (p2 >> 16) | (p3 & 0xFFFF0000u);
        lo.x = (p0 & 0xFFFFu) | (p1 << 16);
        lo.y = (p2 & 0xFFFFu) | (p3 << 16);
        ((uint2*)hhi)[i] = hi;
        ((uint2*)hlo)[i] = lo;
    }
}

__global__ void k_pack_w(const float* __restrict__ Wl, const float* __restrict__ Wr,
                         unsigned short* __restrict__ whi, unsigned short* __restrict__ wlo) {
    int i = blockIdx.x * blockDim.x + threadIdx.x;
    if (i < 128 * 256) {
        int c = i >> 8;
        int k = i & 255;
        float v = (k < 128) ? Wl[c * 128 + k] : Wr[c * 128 + (k - 128)];
        unsigned short hi = bf16_rne(v);
        whi[i] = hi;
        wlo[i] = bf16_rne(v - bf16_f(hi));
    }
}

// ---------------- aggregate (mean over padded CSR, hi-plane only) ----------
// 1 node/wave. Lane = (edge parity h, col-quad c): uint2 load covers cols
// 4c..4c+3 of edge pair (2u+h). Padded rows -> loop always full-width; pad
// src=NN hits the cached zero row. Perm read as uniform uint4 (16B-aligned).
__global__ __launch_bounds__(256) void k_aggregate(const unsigned short* __restrict__ hhi,
        const int* __restrict__ row_start, const int* __restrict__ cnt,
        const unsigned short* __restrict__ perm,
        unsigned short* __restrict__ shi, unsigned short* __restrict__ slo) {
    int wave = __builtin_amdgcn_readfirstlane(threadIdx.x >> 6);
    int lane = threadIdx.x & 63;
    int node = blockIdx.x * 4 + wave;
    if (node >= NN) return;
    int deg = cnt[node];
    int start = row_start[node];              // multiple of 8 -> 16B aligned
    int h16 = (lane >> 5) << 4;               // 0 | 16 : src-extract shift
    int c8  = (lane & 31) << 3;               // byte offset of uint2 in row
    const char* base = (const char*)hhi;      // row stride 256B
    float a0 = 0.f, a1 = 0.f, a2 = 0.f, a3 = 0.f;
    int pdeg = (deg + 7) & ~7;
    const uint4* pp = (const uint4*)(perm + start);
    int j = 0;
    for (; j + 16 <= pdeg; j += 16) {
        uint4 w0 = pp[0], w1 = pp[1]; pp += 2;
        unsigned pw[8] = {w0.x, w0.y, w0.z, w0.w, w1.x, w1.y, w1.z, w1.w};
        uint2 q[8];
#pragma unroll
        for (int u = 0; u < 8; ++u) {
            unsigned src = (pw[u] >> h16) & 0xFFFFu;
            q[u] = *(const uint2*)(base + ((size_t)src << 8) + c8);
        }
#pragma unroll
        for (int u = 0; u < 8; ++u) {
            a0 += __uint_as_float(q[u].x << 16);
            a1 += __uint_as_float(q[u].x & 0xFFFF0000u);
            a2 += __uint_as_float(q[u].y << 16);
            a3 += __uint_as_float(q[u].y & 0xFFFF0000u);
        }
    }
    if (j < pdeg) {                           // at most one 8-step
        uint4 w0 = *pp;
        unsigned pw[4] = {w0.x, w0.y, w0.z, w0.w};
        uint2 q[4];
#pragma unroll
        for (int u = 0; u < 4; ++u) {
            unsigned src = (pw[u] >> h16) & 0xFFFFu;
            q[u] = *(const uint2*)(base + ((size_t)src << 8) + c8);
        }
#pragma unroll
        for (int u = 0; u < 4; ++u) {
            a0 += __uint_as_float(q[u].x << 16);
            a1 += __uint_as_float(q[u].x & 0xFFFF0000u);
            a2 += __uint_as_float(q[u].y << 16);
            a3 += __uint_as_float(q[u].y & 0xFFFF0000u);
        }
    }
    // combine the two edge-parity halves (lane l <-> l^32 hold same cols)
    a0 += __shfl_xor(a0, 32);
    a1 += __shfl_xor(a1, 32);
    a2 += __shfl_xor(a2, 32);
    a3 += __shfl_xor(a3, 32);
    float inv = 1.0f / (float)(deg > 1 ? deg : 1);
    unsigned p0 = pack_split(a0 * inv);       // col 4c
    unsigned p1 = pack_split(a1 * inv);       // col 4c+1
    unsigned p2 = pack_split(a2 * inv);       // col 4c+2
    unsigned p3 = pack_split(a3 * inv);       // col 4c+3
    if (lane < 32) {
        uint2 hi, lo;
        hi.x = (p0 >> 16) | (p1 & 0xFFFF0000u);
        hi.y = (p2 >> 16) | (p3 & 0xFFFF0000u);
        lo.x = (p0 & 0xFFFFu) | (p1 << 16);
        lo.y = (p2 & 0xFFFFu) | (p3 << 16);
        ((uint2*)shi)[(size_t)node * 32 + lane] = hi;
        ((uint2*)slo)[(size_t)node * 32 + lane] = lo;
    }
}

// ---------------- weight-stationary MFMA GEMM (grid-stride) ----------------
// out[n][c] = relu( bias[c] + sum_k [A0|A1][n][k] W[c][k] )
__global__ __launch_bounds__(256, 2) void k_gemm_ws(
        const unsigned short* __restrict__ Ahi0, const unsigned short* __restrict__ Alo0,
        const unsigned short* __restrict__ Ahi1, const unsigned short* __restrict__ Alo1,
        const unsigned short* __restrict__ Whi, const unsigned short* __restrict__ Wlo,
        const float* __restrict__ bias,
        unsigned short* __restrict__ Ohi, unsigned short* __restrict__ Olo) {
    int wave = __builtin_amdgcn_readfirstlane(threadIdx.x >> 6);
    int lane = threadIdx.x & 63;
    int row = lane & 15;
    int kb = lane >> 4;
    int ct0 = wave * 2;

    bf16x8 bh[2][8], bl[2][8];
#pragma unroll
    for (int c = 0; c < 2; ++c)
#pragma unroll
        for (int kc = 0; kc < 8; ++kc) {
            size_t widx = (size_t)((ct0 + c) * 16 + row) * 256 + kc * 32 + kb * 8;
            bh[c][kc] = *(const bf16x8*)(Whi + widx);
            bl[c][kc] = *(const bf16x8*)(Wlo + widx);
        }
    float b0 = bias[ct0 * 16 + row];
    float b1 = bias[ct0 * 16 + 16 + row];

    for (int t = blockIdx.x; t < NTILE; t += gridDim.x) {
        int n0 = t * 16;
        size_t rb = (size_t)(n0 + row) * 128 + kb * 8;
        bf16x8 ah[8], al[8];
#pragma unroll
        for (int kc = 0; kc < 4; ++kc) {
            ah[kc] = *(const bf16x8*)(Ahi0 + rb + kc * 32);
            al[kc] = *(const bf16x8*)(Alo0 + rb + kc * 32);
        }
#pragma unroll
        for (int kc = 0; kc < 4; ++kc) {
            ah[4 + kc] = *(const bf16x8*)(Ahi1 + rb + kc * 32);
            al[4 + kc] = *(const bf16x8*)(Alo1 + rb + kc * 32);
        }
        f32x4 acc0 = {0.f, 0.f, 0.f, 0.f};
        f32x4 acc1 = {0.f, 0.f, 0.f, 0.f};
#pragma unroll
        for (int kc = 0; kc < 8; ++kc) {
            acc0 = __builtin_amdgcn_mfma_f32_16x16x32_bf16(ah[kc], bh[0][kc], acc0, 0, 0, 0);
            acc0 = __builtin_amdgcn_mfma_f32_16x16x32_bf16(al[kc], bh[0][kc], acc0, 0, 0, 0);
            acc0 = __builtin_amdgcn_mfma_f32_16x16x32_bf16(ah[kc], bl[0][kc], acc0, 0, 0, 0);
            acc1 = __builtin_amdgcn_mfma_f32_16x16x32_bf16(ah[kc], bh[1][kc], acc1, 0, 0, 0);
            acc1 = __builtin_amdgcn_mfma_f32_16x16x32_bf16(al[kc], bh[1][kc], acc1, 0, 0, 0);
            acc1 = __builtin_amdgcn_mfma_f32_16x16x32_bf16(ah[kc], bl[1][kc], acc1, 0, 0, 0);
        }
        __syncthreads();   // all waves' reads of this tile's rows precede writes
        int cb0 = ct0 * 16 + row;
#pragma unroll
        for (int r = 0; r < 4; ++r) {
            int n = n0 + kb * 4 + r;         // D: col=lane&15, row=(lane>>4)*4+reg
            size_t ro = (size_t)n * 128;
            unsigned p0 = pack_split(fmaxf(acc0[r] + b0, 0.f));
            unsigned p1 = pack_split(fmaxf(acc1[r] + b1, 0.f));
            Ohi[ro + cb0]      = (unsigned short)(p0 >> 16);
            Olo[ro + cb0]      = (unsigned short)(p0 & 0xFFFFu);
            Ohi[ro + cb0 + 16] = (unsigned short)(p1 >> 16);
            Olo[ro + cb0 + 16] = (unsigned short)(p1 & 0xFFFFu);
        }
    }
}

// layer-2 variant: head fused — out[n] += sum_c relu(h3[n][c]) * Wf[c]
__global__ __launch_bounds__(256, 2) void k_gemm_head(
        const unsigned short* __restrict__ Ahi0, const unsigned short* __restrict__ Alo0,
        const unsigned short* __restrict__ Ahi1, const unsigned short* __restrict__ Alo1,
        const unsigned short* __restrict__ Whi, const unsigned short* __restrict__ Wlo,
        const float* __restrict__ bias, const float* __restrict__ Wf,
        float* __restrict__ out) {
    int wave = __builtin_amdgcn_readfirstlane(threadIdx.x >> 6);
    int lane = threadIdx.x & 63;
    int row = lane & 15;
    int kb = lane >> 4;
    int ct0 = wave * 2;

    bf16x8 bh[2][8], bl[2][8];
#pragma unroll
    for (int c = 0; c < 2; ++c)
#pragma unroll
        for (int kc = 0; kc < 8; ++kc) {
            size_t widx = (size_t)((ct0 + c) * 16 + row) * 256 + kc * 32 + kb * 8;
            bh[c][kc] = *(const bf16x8*)(Whi + widx);
            bl[c][kc] = *(const bf16x8*)(Wlo + widx);
        }
    float b0 = bias[ct0 * 16 + row];
    float b1 = bias[ct0 * 16 + 16 + row];
    float w0 = Wf[ct0 * 16 + row];
    float w1 = Wf[ct0 * 16 + 16 + row];

    for (int t = blockIdx.x; t < NTILE; t += gridDim.x) {
        int n0 = t * 16;
        size_t rb = (size_t)(n0 + row) * 128 + kb * 8;
        bf16x8 ah[8], al[8];
#pragma unroll
        for (int kc = 0; kc < 4; ++kc) {
            ah[kc] = *(const bf16x8*)(Ahi0 + rb + kc * 32);
            al[kc] = *(const bf16x8*)(Alo0 + rb + kc * 32);
        }
#pragma unroll
        for (int kc = 0; kc < 4; ++kc) {
            ah[4 + kc] = *(const bf16x8*)(Ahi1 + rb + kc * 32);
            al[4 + kc] = *(const bf16x8*)(Alo1 + rb + kc * 32);
        }
        f32x4 acc0 = {0.f, 0.f, 0.f, 0.f};
        f32x4 acc1 = {0.f, 0.f, 0.f, 0.f};
#pragma unroll
        for (int kc = 0; kc < 8; ++kc) {
            acc0 = __builtin_amdgcn_mfma_f32_16x16x32_bf16(ah[kc], bh[0][kc], acc0, 0, 0, 0);
            acc0 = __builtin_amdgcn_mfma_f32_16x16x32_bf16(al[kc], bh[0][kc], acc0, 0, 0, 0);
            acc0 = __builtin_amdgcn_mfma_f32_16x16x32_bf16(ah[kc], bl[0][kc], acc0, 0, 0, 0);
            acc1 = __builtin_amdgcn_mfma_f32_16x16x32_bf16(ah[kc], bh[1][kc], acc1, 0, 0, 0);
            acc1 = __builtin_amdgcn_mfma_f32_16x16x32_bf16(al[kc], bh[1][kc], acc1, 0, 0, 0);
            acc1 = __builtin_amdgcn_mfma_f32_16x16x32_bf16(ah[kc], bl[1][kc], acc1, 0, 0, 0);
        }
        float part[4];
#pragma unroll
        for (int r = 0; r < 4; ++r)
            part[r] = fmaxf(acc0[r] + b0, 0.f) * w0 + fmaxf(acc1[r] + b1, 0.f) * w1;
#pragma unroll
        for (int o = 1; o < 16; o <<= 1) {
#pragma unroll
            for (int r = 0; r < 4; ++r) part[r] += __shfl_xor(part[r], o);
        }
        if (row == 0) {
#pragma unroll
            for (int r = 0; r < 4; ++r) atomicAdd(&out[n0 + kb * 4 + r], part[r]);
        }
    }
}

extern "C" void kernel_launch(void* const* d_in, const int* in_sizes, int n_in,
                              void* d_out, int out_size, void* d_ws, size_t ws_size,
                              hipStream_t stream) {
    const float* x   = (const float*)d_in[0];
    const int*   ei  = (const int*)d_in[1];
    const float* Wl0 = (const float*)d_in[2];
    const float* bl0 = (const float*)d_in[3];
    const float* Wr0 = (const float*)d_in[4];
    const float* Wl1 = (const float*)d_in[5];
    const float* bl1 = (const float*)d_in[6];
    const float* Wr1 = (const float*)d_in[7];
    const float* Wl2 = (const float*)d_in[8];
    const float* bl2 = (const float*)d_in[9];
    const float* Wr2 = (const float*)d_in[10];
    const float* Wf  = (const float*)d_in[11];
    const float* bf  = (const float*)d_in[12];
    float* out = (float*)d_out;

    char* p = (char*)d_ws;
    auto alloc = [&](size_t n) { void* r = (void*)p; p += (n + 255) & ~(size_t)255; return r; };
    int*            bcnt      = (int*)alloc(256 * 4);
    int*            cnt       = (int*)alloc((size_t)NN * 4);
    int*            row_start = (int*)alloc((size_t)NN * 4);
    unsigned short* perm      = (unsigned short*)alloc((size_t)NBUCK * PCAP * 2);
    unsigned short* s_hi      = (unsigned short*)alloc((size_t)(NN + 1) * 128 * 2);
    unsigned short* s_lo      = (unsigned short*)alloc((size_t)(NN + 1) * 128 * 2);
    unsigned short* h_hi      = (unsigned short*)alloc((size_t)(NN + 1) * 128 * 2);
    unsigned short* h_lo      = (unsigned short*)alloc((size_t)(NN + 1) * 128 * 2);
    unsigned short* whi       = (unsigned short*)alloc((size_t)3 * 128 * 256 * 2);
    unsigned short* wlo       = (unsigned short*)alloc((size_t)3 * 128 * 256 * 2);
    unsigned*       packed    = (unsigned*)s_hi;  // 4.8MB < 12.8MB; consumed
                                                  // by bucket_csr before agg

    dim3 b256(256);
    // init (out bias, bucket counters, h_hi sentinel row) BEFORE build
    k_init<<<dim3((NN + 255) / 256), b256, 0, stream>>>(out, bf, bcnt, h_hi);
    // CSR build: 2 kernels (was 6)
    k_build_buckets<<<dim3(NBLK), b256, 0, stream>>>(ei, bcnt, packed);
    k_bucket_csr<<<dim3(NBUCK), b256, 0, stream>>>(packed, bcnt, perm, cnt, row_start);

    // packing
    k_pack_x<<<dim3((NN * 128 / 4 + 255) / 256), b256, 0, stream>>>(x, h_hi, h_lo);
    k_pack_w<<<dim3(128), b256, 0, stream>>>(Wl0, Wr0, whi + 0 * 32768, wlo + 0 * 32768);
    k_pack_w<<<dim3(128), b256, 0, stream>>>(Wl1, Wr1, whi + 1 * 32768, wlo + 1 * 32768);
    k_pack_w<<<dim3(128), b256, 0, stream>>>(Wl2, Wr2, whi + 2 * 32768, wlo + 2 * 32768);

    dim3 gAgg((NN + 3) / 4);    // 1 node/wave, 4 per block
    dim3 gGemm(512);            // 2 blocks/CU; grid-stride over 3125 tiles

    // layer 0
    k_aggregate<<<gAgg, b256, 0, stream>>>(h_hi, row_start, cnt, perm, s_hi, s_lo);
    k_gemm_ws<<<gGemm, b256, 0, stream>>>(s_hi, s_lo, h_hi, h_lo,
                                          whi + 0 * 32768, wlo + 0 * 32768, bl0, h_hi, h_lo);
    // layer 1 (in place)
    k_aggregate<<<gAgg, b256, 0, stream>>>(h_hi, row_start, cnt, perm, s_hi, s_lo);
    k_gemm_ws<<<gGemm, b256, 0, stream>>>(s_hi, s_lo, h_hi, h_lo,
                                          whi + 1 * 32768, wlo + 1 * 32768, bl1, h_hi, h_lo);
    // layer 2 + fused head
    k_aggregate<<<gAgg, b256, 0, stream>>>(h_hi, row_start, cnt, perm, s_hi, s_lo);
    k_gemm_head<<<gGemm, b256, 0, stream>>>(s_hi, s_lo, h_hi, h_lo,
                                            whi + 2 * 32768, wlo + 2 * 32768, bl2, Wf, out);
}

// Round 2
// 284.712 us; speedup vs baseline: 1.1750x; 1.0990x over previous
//
#include <hip/hip_runtime.h>
#include <hip/hip_bf16.h>

// GraphSage: 3x SAGEConv(mean) + linear head.
// r19: GEMM latency-pipelined + s_lo plane dropped + uint4 gather.
//   - GEMM double-buffers the A-tile across the grid-stride loop: tile t+512's
//     12 dwordx4 loads issue BEFORE tile t's MFMA block, hiding ~L3 latency
//     under MFMA+barrier+store. In-place safe: tile tn's rows are only ever
//     written by the same block (tn = blockIdx + k*512), later; the current
//     barrier/stores touch disjoint rows.
//   - s_lo (mean residual plane) dropped: mean is already built from bf16
//     inputs (2^-9); its own bf16 rounding adds ~2.3e-4/layer in quadrature.
//     Saves 12.8MB wr + 12.8MB rd per layer, MFMA 48->40/tile, and frees the
//     VGPRs needed for the GEMM double-buffer (128 B + 72 A + acc ~= 250).
//   - aggregate gathers via uint4: lane=(edge group eg, col chunk cl); one
//     wave-load covers FOUR 256B rows (was 2 with uint2) -> half the VMEM
//     instrs + addr VALU, same bytes in flight. eg-reduce = 2 shfl_xor.
//   - launches 13 -> 10: init merged into pack kernel; 3x pack_w -> 1.
// CSR rows padded to mult of 8 with sentinel src=NN (zeroed row; L1-resident).
// CSR build: fixed bucket regions + LDS hist + one atomicAdd range reserve.
// Structure: SEPARATE aggregate and GEMM (r12 fusion starved the gather).
// XCD affinity NOT controllable from HIP (r14/r15) — do not retry.
// fp8 gather REJECTED: mean-of-16 e4m3 noise ~4.3e-3 > 3.85e-3 threshold.
// packed[] aliases s_hi (disjoint lifetime: consumed by bucket_csr pre-agg).

constexpr int NN = 50000;
constexpr int NE = 800000;
constexpr int NTILE = NN / 16;          // 3125 exact
constexpr int EPB = 4096;
constexpr int NBLK = (NE + EPB - 1) / EPB;   // 196
constexpr int NBUCK = 196;                   // ceil(NN/256)
constexpr int BCAP = 6144;   // packed bucket capacity (edges); mean 4096
constexpr int PCAP = 6144;   // padded perm bucket capacity; mean ~4992, mult of 8
constexpr int GGRID = 512;   // GEMM grid (2 blocks/CU)

using bf16x8 = __attribute__((ext_vector_type(8))) short;
using f32x4  = __attribute__((ext_vector_type(4))) float;

__device__ __forceinline__ unsigned short bf16_rne(float f) {
    unsigned u = __float_as_uint(f);
    unsigned r = (u + 0x7FFFu + ((u >> 16) & 1u)) >> 16;
    return (unsigned short)r;
}
__device__ __forceinline__ float bf16_f(unsigned short h) {
    return __uint_as_float(((unsigned)h) << 16);
}
__device__ __forceinline__ unsigned pack_split(float v) {
    unsigned short hi = bf16_rne(v);
    float r = v - bf16_f(hi);
    unsigned short lo = bf16_rne(r);
    return (((unsigned)hi) << 16) | (unsigned)lo;
}

// ------------- pack x -> planar split bf16, + all init work ---------------

__global__ __launch_bounds__(256) void k_packinit(const float* __restrict__ x,
        unsigned short* __restrict__ hhi, unsigned short* __restrict__ hlo,
        float* __restrict__ out, const float* __restrict__ bf,
        int* __restrict__ bcnt) {
    int i = blockIdx.x * blockDim.x + threadIdx.x;
    constexpr int TOT = NN * 128 / 4;
    if (i < TOT) {
        float4 v = ((const float4*)x)[i];
        unsigned p0 = pack_split(v.x), p1 = pack_split(v.y);
        unsigned p2 = pack_split(v.z), p3 = pack_split(v.w);
        uint2 hi, lo;
        hi.x = (p0 >> 16) | (p1 & 0xFFFF0000u);
        hi.y = (p2 >> 16) | (p3 & 0xFFFF0000u);
        lo.x = (p0 & 0xFFFFu) | (p1 << 16);
        lo.y = (p2 & 0xFFFFu) | (p3 << 16);
        ((uint2*)hhi)[i] = hi;
        ((uint2*)hlo)[i] = lo;
    }
    if (i < NN) out[i] = bf[0];
    if (i < 256) bcnt[i] = 0;
    if (i < 128) hhi[(size_t)NN * 128 + i] = 0;   // sentinel row for pad edges
}

// ---------------- CSR build: one-pass bucket scatter ----------------

__global__ __launch_bounds__(256) void k_build_buckets(const int* __restrict__ ei,
        int* __restrict__ bcnt, unsigned* __restrict__ packed) {
    __shared__ unsigned stage[EPB];   // 16KB
    __shared__ int h[256];
    __shared__ int cur[256];
    int t = threadIdx.x;
    h[t] = 0;
    __syncthreads();
    int e0 = blockIdx.x * EPB;
    int e1 = e0 + EPB; if (e1 > NE) e1 = NE;
    for (int e = e0 + t; e < e1; e += 256) {
        int s = ei[e];
        int d = ei[NE + e];
        stage[e - e0] = ((unsigned)d << 16) | (unsigned)s;
        atomicAdd(&h[d >> 8], 1);
    }
    __syncthreads();
    if (t < NBUCK) cur[t] = t * BCAP + atomicAdd(&bcnt[t], h[t]);
    __syncthreads();
    for (int e = e0 + t; e < e1; e += 256) {
        unsigned r = stage[e - e0];
        int pos = atomicAdd(&cur[r >> 24], 1);   // bucket = d>>8 = r>>24
        packed[pos] = r;
    }
}

// Per bucket: LDS counting sort by (d&255) with per-node padding to mult of 8;
// pad slots filled with sentinel NN. row_start points into b*PCAP region.
__global__ __launch_bounds__(256) void k_bucket_csr(const unsigned* __restrict__ packed,
        const int* __restrict__ bcnt, unsigned short* __restrict__ perm,
        int* __restrict__ cnt, int* __restrict__ row_start) {
    __shared__ unsigned recs[BCAP];       // 24KB
    __shared__ unsigned short outs[PCAP]; // 12KB
    __shared__ int cntL[256];
    __shared__ int ws[4];
    __shared__ int totS;
    int b = blockIdx.x;
    int m = bcnt[b];
    if (m > BCAP) m = BCAP;
    int t = threadIdx.x;
    cntL[t] = 0;
    __syncthreads();
    int lo = b * BCAP;
    for (int i = t; i < m; i += 256) {
        unsigned r = packed[lo + i];
        recs[i] = r;
        atomicAdd(&cntL[(r >> 16) & 255], 1);
    }
    __syncthreads();
    int lane = t & 63, wave = t >> 6;
    int orig = cntL[t];
    int pc = (orig + 7) & ~7;            // padded per-node degree
    int v = pc;
    for (int o = 1; o < 64; o <<= 1) { int u = __shfl_up(v, o); if (lane >= o) v += u; }
    if (lane == 63) ws[wave] = v;
    __syncthreads();
    int off = 0;
    for (int w = 0; w < wave; ++w) off += ws[w];
    int st = v + off - pc;               // exclusive scan of padded degrees
    int node = b * 256 + t;
    if (node < NN) { cnt[node] = orig; row_start[node] = b * PCAP + st; }
    if (t == 255) totS = st + pc;
    __syncthreads();
    cntL[t] = st;
    __syncthreads();
    for (int i = t; i < m; i += 256) {
        unsigned r = recs[i];
        int pos = atomicAdd(&cntL[(r >> 16) & 255], 1);
        outs[pos] = (unsigned short)(r & 0xFFFFu);
    }
    for (int i = st + orig; i < st + pc; ++i) outs[i] = (unsigned short)NN;
    __syncthreads();
    int totp = totS;
    for (int i = t; i < totp; i += 256)
        perm[b * PCAP + i] = outs[i];
}

// ---------------- pack all 3 layers' weights (1 kernel) ----------------

__global__ __launch_bounds__(256) void k_pack_w3(
        const float* __restrict__ Wl0, const float* __restrict__ Wr0,
        const float* __restrict__ Wl1, const float* __restrict__ Wr1,
        const float* __restrict__ Wl2, const float* __restrict__ Wr2,
        unsigned short* __restrict__ whi, unsigned short* __restrict__ wlo) {
    int layer = blockIdx.x >> 7;
    int i = (blockIdx.x & 127) * 256 + threadIdx.x;     // 0..32767
    const float* Wl = (layer == 0) ? Wl0 : (layer == 1) ? Wl1 : Wl2;
    const float* Wr = (layer == 0) ? Wr0 : (layer == 1) ? Wr1 : Wr2;
    int c = i >> 8;
    int k = i & 255;
    float v = (k < 128) ? Wl[c * 128 + k] : Wr[c * 128 + (k - 128)];
    unsigned short hi = bf16_rne(v);
    whi[layer * 32768 + i] = hi;
    wlo[layer * 32768 + i] = bf16_rne(v - bf16_f(hi));
}

// ---------------- aggregate (mean over padded CSR, hi-plane only) ----------
// 1 node/wave. lane = (eg = lane>>4: edge group, cl = lane&15: 16B col chunk).
// One uint4 wave-load covers FOUR 256B rows. eg-reduce = shfl_xor 16, 32.
__global__ __launch_bounds__(256) void k_aggregate(const unsigned short* __restrict__ hhi,
        const int* __restrict__ row_start, const int* __restrict__ cnt,
        const unsigned short* __restrict__ perm,
        unsigned short* __restrict__ shi) {
    int wave = __builtin_amdgcn_readfirstlane(threadIdx.x >> 6);
    int lane = threadIdx.x & 63;
    int node = blockIdx.x * 4 + wave;
    if (node >= NN) return;
    int deg = cnt[node];
    int start = row_start[node];              // multiple of 8 -> 16B aligned
    int eg = lane >> 4;
    int hsh = (eg & 1) << 4;                  // ushort half within u32
    bool egHi = (eg & 2) != 0;                // which u32 of the pair
    int c16 = (lane & 15) << 4;               // byte offset of uint4 in row
    const char* base = (const char*)hhi;      // row stride 256B
    float a0=0.f,a1=0.f,a2=0.f,a3=0.f,a4=0.f,a5=0.f,a6=0.f,a7=0.f;
#define ACC8(q) { a0 += __uint_as_float((q).x << 16); a1 += __uint_as_float((q).x & 0xFFFF0000u); \
                  a2 += __uint_as_float((q).y << 16); a3 += __uint_as_float((q).y & 0xFFFF0000u); \
                  a4 += __uint_as_float((q).z << 16); a5 += __uint_as_float((q).z & 0xFFFF0000u); \
                  a6 += __uint_as_float((q).w << 16); a7 += __uint_as_float((q).w & 0xFFFF0000u); }
#define GATH(w) (*(const uint4*)(base + ((size_t)(((w) >> hsh) & 0xFFFFu) << 8) + c16))
    int pdeg = (deg + 7) & ~7;
    const uint4* pp = (const uint4*)(perm + start);
    int j = 0;
    for (; j + 16 <= pdeg; j += 16) {
        uint4 P0 = pp[0], P1 = pp[1]; pp += 2;
        unsigned w0 = egHi ? P0.y : P0.x;     // edges j+0+eg .. (load 0)
        unsigned w1 = egHi ? P0.w : P0.z;     // edges j+4+eg
        unsigned w2 = egHi ? P1.y : P1.x;     // edges j+8+eg
        unsigned w3 = egHi ? P1.w : P1.z;     // edges j+12+eg
        uint4 q0 = GATH(w0);
        uint4 q1 = GATH(w1);
        uint4 q2 = GATH(w2);
        uint4 q3 = GATH(w3);
        ACC8(q0); ACC8(q1); ACC8(q2); ACC8(q3);
    }
    if (j < pdeg) {                           // exactly one 8-edge step
        uint4 P0 = *pp;
        unsigned w0 = egHi ? P0.y : P0.x;
        unsigned w1 = egHi ? P0.w : P0.z;
        uint4 q0 = GATH(w0);
        uint4 q1 = GATH(w1);
        ACC8(q0); ACC8(q1);
    }
#undef GATH
#undef ACC8
    // reduce across the 4 edge groups (cl preserved: ^16 flips eg bit0, ^32 bit1)
    a0 += __shfl_xor(a0, 16); a1 += __shfl_xor(a1, 16);
    a2 += __shfl_xor(a2, 16); a3 += __shfl_xor(a3, 16);
    a4 += __shfl_xor(a4, 16); a5 += __shfl_xor(a5, 16);
    a6 += __shfl_xor(a6, 16); a7 += __shfl_xor(a7, 16);
    a0 += __shfl_xor(a0, 32); a1 += __shfl_xor(a1, 32);
    a2 += __shfl_xor(a2, 32); a3 += __shfl_xor(a3, 32);
    a4 += __shfl_xor(a4, 32); a5 += __shfl_xor(a5, 32);
    a6 += __shfl_xor(a6, 32); a7 += __shfl_xor(a7, 32);
    float inv = 1.0f / (float)(deg > 1 ? deg : 1);
    if (eg == 0) {
        uint4 o;
        o.x = (unsigned)bf16_rne(a0 * inv) | ((unsigned)bf16_rne(a1 * inv) << 16);
        o.y = (unsigned)bf16_rne(a2 * inv) | ((unsigned)bf16_rne(a3 * inv) << 16);
        o.z = (unsigned)bf16_rne(a4 * inv) | ((unsigned)bf16_rne(a5 * inv) << 16);
        o.w = (unsigned)bf16_rne(a6 * inv) | ((unsigned)bf16_rne(a7 * inv) << 16);
        ((uint4*)shi)[(size_t)node * 16 + (lane & 15)] = o;
    }
}

// ---------------- weight-stationary MFMA GEMM (pipelined grid-stride) ------
// out[n][c] = relu( bias[c] + sum_k [S|H][n][k] W[c][k] )
// A = {s_hi (mean, bf16), h_hi+h_lo (x, split)}. 12 dwordx4 A loads/tile,
// double-buffered across the grid-stride loop (prefetch t+512 before MFMA(t)).
#define GEMM_PROLOG \
    int wave = __builtin_amdgcn_readfirstlane(threadIdx.x >> 6); \
    int lane = threadIdx.x & 63; \
    int row = lane & 15; \
    int kb = lane >> 4; \
    int ct0 = wave * 2; \
    bf16x8 bh[2][8], bl[2][8]; \
    _Pragma("unroll") \
    for (int c = 0; c < 2; ++c) \
        _Pragma("unroll") \
        for (int kc = 0; kc < 8; ++kc) { \
            size_t widx = (size_t)((ct0 + c) * 16 + row) * 256 + kc * 32 + kb * 8; \
            bh[c][kc] = *(const bf16x8*)(Whi + widx); \
            bl[c][kc] = *(const bf16x8*)(Wlo + widx); \
        } \
    float b0 = bias[ct0 * 16 + row]; \
    float b1 = bias[ct0 * 16 + 16 + row];

#define LOADT(AS, AH, AL, t) { \
        size_t rb = (size_t)((t) * 16 + row) * 128 + kb * 8; \
        _Pragma("unroll") \
        for (int kc = 0; kc < 4; ++kc) { \
            AS[kc] = *(const bf16x8*)(Ash + rb + kc * 32); \
            AH[kc] = *(const bf16x8*)(Ahh + rb + kc * 32); \
            AL[kc] = *(const bf16x8*)(Ahl + rb + kc * 32); \
        } }

#define MFMA40(AS, AH, AL) \
        f32x4 acc0 = {0.f, 0.f, 0.f, 0.f}; \
        f32x4 acc1 = {0.f, 0.f, 0.f, 0.f}; \
        _Pragma("unroll") \
        for (int kc = 0; kc < 4; ++kc) { \
            acc0 = __builtin_amdgcn_mfma_f32_16x16x32_bf16(AS[kc], bh[0][kc], acc0, 0, 0, 0); \
            acc0 = __builtin_amdgcn_mfma_f32_16x16x32_bf16(AS[kc], bl[0][kc], acc0, 0, 0, 0); \
            acc1 = __builtin_amdgcn_mfma_f32_16x16x32_bf16(AS[kc], bh[1][kc], acc1, 0, 0, 0); \
            acc1 = __builtin_amdgcn_mfma_f32_16x16x32_bf16(AS[kc], bl[1][kc], acc1, 0, 0, 0); \
        } \
        _Pragma("unroll") \
        for (int kc = 0; kc < 4; ++kc) { \
            acc0 = __builtin_amdgcn_mfma_f32_16x16x32_bf16(AH[kc], bh[0][4 + kc], acc0, 0, 0, 0); \
            acc0 = __builtin_amdgcn_mfma_f32_16x16x32_bf16(AL[kc], bh[0][4 + kc], acc0, 0, 0, 0); \
            acc0 = __builtin_amdgcn_mfma_f32_16x16x32_bf16(AH[kc], bl[0][4 + kc], acc0, 0, 0, 0); \
            acc1 = __builtin_amdgcn_mfma_f32_16x16x32_bf16(AH[kc], bh[1][4 + kc], acc1, 0, 0, 0); \
            acc1 = __builtin_amdgcn_mfma_f32_16x16x32_bf16(AL[kc], bh[1][4 + kc], acc1, 0, 0, 0); \
            acc1 = __builtin_amdgcn_mfma_f32_16x16x32_bf16(AH[kc], bl[1][4 + kc], acc1, 0, 0, 0); \
        }

__global__ __launch_bounds__(256, 2) void k_gemm_ws(
        const unsigned short* __restrict__ Ash,
        const unsigned short* __restrict__ Ahh, const unsigned short* __restrict__ Ahl,
        const unsigned short* __restrict__ Whi, const unsigned short* __restrict__ Wlo,
        const float* __restrict__ bias,
        unsigned short* __restrict__ Ohi, unsigned short* __restrict__ Olo) {
    GEMM_PROLOG
#define STEP(AS, AH, AL, t) { \
        MFMA40(AS, AH, AL) \
        __syncthreads();   /* all waves' reads of tile t precede its writes */ \
        int cb0 = ct0 * 16 + row; \
        _Pragma("unroll") \
        for (int r = 0; r < 4; ++r) { \
            size_t ro = (size_t)((t) * 16 + kb * 4 + r) * 128; \
            unsigned p0 = pack_split(fmaxf(acc0[r] + b0, 0.f)); \
            unsigned p1 = pack_split(fmaxf(acc1[r] + b1, 0.f)); \
            Ohi[ro + cb0]      = (unsigned short)(p0 >> 16); \
            Olo[ro + cb0]      = (unsigned short)(p0 & 0xFFFFu); \
            Ohi[ro + cb0 + 16] = (unsigned short)(p1 >> 16); \
            Olo[ro + cb0 + 16] = (unsigned short)(p1 & 0xFFFFu); \
        } }
    bf16x8 sA[4], hA[4], lA[4], sB[4], hB[4], lB[4];
    int t = blockIdx.x;
    LOADT(sA, hA, lA, t)
    int tn = t + GGRID;
    for (;;) {
        if (tn < NTILE) LOADT(sB, hB, lB, tn)
        STEP(sA, hA, lA, t)
        if (tn >= NTILE) break;
        t = tn; tn += GGRID;
        if (tn < NTILE) LOADT(sA, hA, lA, tn)
        STEP(sB, hB, lB, t)
        if (tn >= NTILE) break;
        t = tn; tn += GGRID;
    }
#undef STEP
}

// layer-2 variant: head fused — out[n] += sum_c relu(h3[n][c]) * Wf[c]
__global__ __launch_bounds__(256, 2) void k_gemm_head(
        const unsigned short* __restrict__ Ash,
        const unsigned short* __restrict__ Ahh, const unsigned short* __restrict__ Ahl,
        const unsigned short* __restrict__ Whi, const unsigned short* __restrict__ Wlo,
        const float* __restrict__ bias, const float* __restrict__ Wf,
        float* __restrict__ out) {
    GEMM_PROLOG
    float w0 = Wf[ct0 * 16 + row];
    float w1 = Wf[ct0 * 16 + 16 + row];
#define HSTEP(AS, AH, AL, t) { \
        MFMA40(AS, AH, AL) \
        float part[4]; \
        _Pragma("unroll") \
        for (int r = 0; r < 4; ++r) \
            part[r] = fmaxf(acc0[r] + b0, 0.f) * w0 + fmaxf(acc1[r] + b1, 0.f) * w1; \
        _Pragma("unroll") \
        for (int o = 1; o < 16; o <<= 1) { \
            _Pragma("unroll") \
            for (int r = 0; r < 4; ++r) part[r] += __shfl_xor(part[r], o); \
        } \
        if (row == 0) { \
            _Pragma("unroll") \
            for (int r = 0; r < 4; ++r) atomicAdd(&out[(t) * 16 + kb * 4 + r], part[r]); \
        } }
    bf16x8 sA[4], hA[4], lA[4], sB[4], hB[4], lB[4];
    int t = blockIdx.x;
    LOADT(sA, hA, lA, t)
    int tn = t + GGRID;
    for (;;) {
        if (tn < NTILE) LOADT(sB, hB, lB, tn)
        HSTEP(sA, hA, lA, t)
        if (tn >= NTILE) break;
        t = tn; tn += GGRID;
        if (tn < NTILE) LOADT(sA, hA, lA, tn)
        HSTEP(sB, hB, lB, t)
        if (tn >= NTILE) break;
        t = tn; tn += GGRID;
    }
#undef HSTEP
}

extern "C" void kernel_launch(void* const* d_in, const int* in_sizes, int n_in,
                              void* d_out, int out_size, void* d_ws, size_t ws_size,
                              hipStream_t stream) {
    const float* x   = (const float*)d_in[0];
    const int*   ei  = (const int*)d_in[1];
    const float* Wl0 = (const float*)d_in[2];
    const float* bl0 = (const float*)d_in[3];
    const float* Wr0 = (const float*)d_in[4];
    const float* Wl1 = (const float*)d_in[5];
    const float* bl1 = (const float*)d_in[6];
    const float* Wr1 = (const float*)d_in[7];
    const float* Wl2 = (const float*)d_in[8];
    const float* bl2 = (const float*)d_in[9];
    const float* Wr2 = (const float*)d_in[10];
    const float* Wf  = (const float*)d_in[11];
    const float* bf  = (const float*)d_in[12];
    float* out = (float*)d_out;

    char* p = (char*)d_ws;
    auto alloc = [&](size_t n) { void* r = (void*)p; p += (n + 255) & ~(size_t)255; return r; };
    int*            bcnt      = (int*)alloc(256 * 4);
    int*            cnt       = (int*)alloc((size_t)NN * 4);
    int*            row_start = (int*)alloc((size_t)NN * 4);
    unsigned short* perm      = (unsigned short*)alloc((size_t)NBUCK * PCAP * 2);
    unsigned short* s_hi      = (unsigned short*)alloc((size_t)(NN + 1) * 128 * 2);
    unsigned short* h_hi      = (unsigned short*)alloc((size_t)(NN + 1) * 128 * 2);
    unsigned short* h_lo      = (unsigned short*)alloc((size_t)(NN + 1) * 128 * 2);
    unsigned short* whi       = (unsigned short*)alloc((size_t)3 * 128 * 256 * 2);
    unsigned short* wlo       = (unsigned short*)alloc((size_t)3 * 128 * 256 * 2);
    unsigned*       packed    = (unsigned*)s_hi;  // 4.8MB < 12.8MB; consumed
                                                  // by bucket_csr before agg

    dim3 b256(256);
    // pack x + all init (out bias, bcnt, sentinel row) — must precede build
    k_packinit<<<dim3((NN * 128 / 4 + 255) / 256), b256, 0, stream>>>(
        x, h_hi, h_lo, out, bf, bcnt);
    // CSR build: 2 kernels
    k_build_buckets<<<dim3(NBLK), b256, 0, stream>>>(ei, bcnt, packed);
    k_bucket_csr<<<dim3(NBUCK), b256, 0, stream>>>(packed, bcnt, perm, cnt, row_start);
    // weights (all 3 layers, 1 kernel)
    k_pack_w3<<<dim3(384), b256, 0, stream>>>(Wl0, Wr0, Wl1, Wr1, Wl2, Wr2, whi, wlo);

    dim3 gAgg((NN + 3) / 4);    // 1 node/wave, 4 per block
    dim3 gGemm(GGRID);          // 2 blocks/CU; grid-stride over 3125 tiles

    // layer 0
    k_aggregate<<<gAgg, b256, 0, stream>>>(h_hi, row_start, cnt, perm, s_hi);
    k_gemm_ws<<<gGemm, b256, 0, stream>>>(s_hi, h_hi, h_lo,
                                          whi + 0 * 32768, wlo + 0 * 32768, bl0, h_hi, h_lo);
    // layer 1 (in place)
    k_aggregate<<<gAgg, b256, 0, stream>>>(h_hi, row_start, cnt, perm, s_hi);
    k_gemm_ws<<<gGemm, b256, 0, stream>>>(s_hi, h_hi, h_lo,
                                          whi + 1 * 32768, wlo + 1 * 32768, bl1, h_hi, h_lo);
    // layer 2 + fused head
    k_aggregate<<<gAgg, b256, 0, stream>>>(h_hi, row_start, cnt, perm, s_hi);
    k_gemm_head<<<gGemm, b256, 0, stream>>>(s_hi, h_hi, h_lo,
                                            whi + 2 * 32768, wlo + 2 * 32768, bl2, Wf, out);
}